// Round 7
// baseline (407.533 us; speedup 1.0000x reference)
//
#include <hip/hip_runtime.h>
#include <math.h>

#define BDIM 2
#define SDIM 4096
#define DMODEL 512
#define NHEAD 8
#define DHEAD 64
#define MROWS (BDIM * SDIM)  // 8192

typedef __attribute__((ext_vector_type(8))) short short8;
typedef __attribute__((ext_vector_type(4))) float f32x4;
typedef __attribute__((ext_vector_type(16))) float f32x16;
typedef __attribute__((ext_vector_type(4))) int i32x4;

#define MFMA16(a, b, c) __builtin_amdgcn_mfma_f32_16x16x32_bf16((a), (b), (c), 0, 0, 0)
#define MFMA32(a, b, c) __builtin_amdgcn_mfma_f32_32x32x16_bf16((a), (b), (c), 0, 0, 0)
#define EXP2F(x) __builtin_amdgcn_exp2f(x)

#define SCALE2 0.18033688011112042f  // 0.125 * log2(e)
#define MASKMUL -1.442695040e9f      // -1e9 * log2(e)
#define M0C 16.0f                    // fixed softmax shift (2^-M0 cancels in O/l)

// Truncation split: x = h + l with h = top 16 bits (exact subtraction).
__device__ inline void bf16_split(float x, short& h, short& l) {
  unsigned u = __float_as_uint(x);
  h = (short)(u >> 16);
  float hf = __uint_as_float(u & 0xffff0000u);
  l = (short)(__float_as_uint(x - hf) >> 16);
}

// ---------------------------------------------------------------------------
// One-shot weight prep: W[k][n] fp32 -> Wt_h[n][k], Wt_l[n][k] bf16 h/l.
// ---------------------------------------------------------------------------
__global__ __launch_bounds__(256) void wsplit_kernel(
    const float* __restrict__ W0, const float* __restrict__ W1,
    const float* __restrict__ W2, const float* __restrict__ W3,
    short* __restrict__ T0h, short* __restrict__ T0l, short* __restrict__ T1h,
    short* __restrict__ T1l, short* __restrict__ T2h, short* __restrict__ T2l,
    short* __restrict__ T3h, short* __restrict__ T3l) {
  __shared__ short Th[64 * 72], Tl[64 * 72];
  const int tid = threadIdx.x;
  const int k0 = blockIdx.x * 64;
  const int n0 = blockIdx.y * 64;
  const int z = blockIdx.z;
  const float* W = (z == 0) ? W0 : (z == 1) ? W1 : (z == 2) ? W2 : W3;
  short* Oh = (z == 0) ? T0h : (z == 1) ? T1h : (z == 2) ? T2h : T3h;
  short* Ol = (z == 0) ? T0l : (z == 1) ? T1l : (z == 2) ? T2l : T3l;

  {
    const int r = tid >> 2;          // k row 0..63
    const int c16 = (tid & 3) * 16;  // n chunk
    short8 h0, h1, l0, l1;
#pragma unroll
    for (int g = 0; g < 2; g++) {
      const f32x4 a = *(const f32x4*)(W + (size_t)(k0 + r) * DMODEL + n0 + c16 + g * 8);
      const f32x4 b = *(const f32x4*)(W + (size_t)(k0 + r) * DMODEL + n0 + c16 + g * 8 + 4);
      short8& hh = g ? h1 : h0;
      short8& ll = g ? l1 : l0;
#pragma unroll
      for (int j = 0; j < 4; j++) {
        short x, y;
        bf16_split(a[j], x, y);
        hh[j] = x;
        ll[j] = y;
        bf16_split(b[j], x, y);
        hh[4 + j] = x;
        ll[4 + j] = y;
      }
    }
    *(short8*)&Th[r * 72 + c16] = h0;
    *(short8*)&Th[r * 72 + c16 + 8] = h1;
    *(short8*)&Tl[r * 72 + c16] = l0;
    *(short8*)&Tl[r * 72 + c16 + 8] = l1;
  }
  __syncthreads();
  {
    const int n = tid >> 2;           // n row of Wt
    const int kc = (tid & 3) * 16;    // k chunk
    short8 h0, h1, l0, l1;
#pragma unroll
    for (int i = 0; i < 8; i++) {
      h0[i] = Th[(kc + i) * 72 + n];
      h1[i] = Th[(kc + 8 + i) * 72 + n];
      l0[i] = Tl[(kc + i) * 72 + n];
      l1[i] = Tl[(kc + 8 + i) * 72 + n];
    }
    short* dh = Oh + (size_t)(n0 + n) * DMODEL + k0 + kc;
    short* dl = Ol + (size_t)(n0 + n) * DMODEL + k0 + kc;
    *(short8*)dh = h0;
    *(short8*)(dh + 8) = h1;
    *(short8*)dl = l0;
    *(short8*)(dl + 8) = l1;
  }
}

// ---------------------------------------------------------------------------
// MFMA bf16x3 GEMM (16x16x32): out = X @ W + bias, Wt pre-split/transposed.
// MODE 0: fp32 out [M,DM].  MODE 1: bf16 h/l split outputs in [B,H,S,D].
// ---------------------------------------------------------------------------
template <int MODE>
__global__ __launch_bounds__(256, 4) void proj_mfma_kernel(
    const float* __restrict__ X, const short* __restrict__ Wth,
    const short* __restrict__ Wtl, const float* __restrict__ bias,
    float* __restrict__ out, short* __restrict__ oh, short* __restrict__ ol) {
  __shared__ short Xh[64 * 72], Xl[64 * 72];
  __shared__ short Wh[64 * 72], Wl[64 * 72];

  const int tid = threadIdx.x;
  const int lane = tid & 63;
  const int w = tid >> 6;
  const int lane15 = lane & 15;
  const int quad = lane >> 4;
  const int wm = (w >> 1) * 32;
  const int wn = (w & 1) * 32;
  const int m0 = blockIdx.x * 64;
  const int n0 = blockIdx.y * 64;

  f32x4 c[2][2];
#pragma unroll
  for (int mt = 0; mt < 2; mt++)
#pragma unroll
    for (int nt = 0; nt < 2; nt++) c[mt][nt] = (f32x4){0.f, 0.f, 0.f, 0.f};

  const int sr = tid >> 2;
  const int sc16 = (tid & 3) * 16;

  for (int k0 = 0; k0 < DMODEL; k0 += 64) {
    {
      short8 h0, h1, l0, l1;
#pragma unroll
      for (int g = 0; g < 2; g++) {
        const f32x4 a =
            *(const f32x4*)(X + (size_t)(m0 + sr) * DMODEL + k0 + sc16 + g * 8);
        const f32x4 b = *(const f32x4*)(X + (size_t)(m0 + sr) * DMODEL + k0 +
                                        sc16 + g * 8 + 4);
        short8& hh = g ? h1 : h0;
        short8& ll = g ? l1 : l0;
#pragma unroll
        for (int j = 0; j < 4; j++) {
          short x, y;
          bf16_split(a[j], x, y);
          hh[j] = x;
          ll[j] = y;
          bf16_split(b[j], x, y);
          hh[4 + j] = x;
          ll[4 + j] = y;
        }
      }
      *(short8*)&Xh[sr * 72 + sc16] = h0;
      *(short8*)&Xh[sr * 72 + sc16 + 8] = h1;
      *(short8*)&Xl[sr * 72 + sc16] = l0;
      *(short8*)&Xl[sr * 72 + sc16 + 8] = l1;

      const short* wsh = Wth + (size_t)(n0 + sr) * DMODEL + k0 + sc16;
      const short* wsl = Wtl + (size_t)(n0 + sr) * DMODEL + k0 + sc16;
      *(short8*)&Wh[sr * 72 + sc16] = *(const short8*)wsh;
      *(short8*)&Wh[sr * 72 + sc16 + 8] = *(const short8*)(wsh + 8);
      *(short8*)&Wl[sr * 72 + sc16] = *(const short8*)wsl;
      *(short8*)&Wl[sr * 72 + sc16 + 8] = *(const short8*)(wsl + 8);
    }
    __syncthreads();

#pragma unroll
    for (int ks = 0; ks < 2; ks++) {
      short8 ah[2], al[2], bh[2], bl[2];
#pragma unroll
      for (int mt = 0; mt < 2; mt++) {
        const int xo = (wm + mt * 16 + lane15) * 72 + ks * 32 + quad * 8;
        ah[mt] = *(const short8*)&Xh[xo];
        al[mt] = *(const short8*)&Xl[xo];
      }
#pragma unroll
      for (int nt = 0; nt < 2; nt++) {
        const int wo = (wn + nt * 16 + lane15) * 72 + ks * 32 + quad * 8;
        bh[nt] = *(const short8*)&Wh[wo];
        bl[nt] = *(const short8*)&Wl[wo];
      }
#pragma unroll
      for (int mt = 0; mt < 2; mt++)
#pragma unroll
        for (int nt = 0; nt < 2; nt++) {
          c[mt][nt] = MFMA16(ah[mt], bh[nt], c[mt][nt]);
          c[mt][nt] = MFMA16(ah[mt], bl[nt], c[mt][nt]);
          c[mt][nt] = MFMA16(al[mt], bh[nt], c[mt][nt]);
        }
    }
    __syncthreads();
  }

#pragma unroll
  for (int nt = 0; nt < 2; nt++) {
    const int n = n0 + wn + nt * 16 + lane15;
    const float bb = bias[n];
#pragma unroll
    for (int mt = 0; mt < 2; mt++)
#pragma unroll
      for (int r = 0; r < 4; r++) {
        const int m = m0 + wm + mt * 16 + quad * 4 + r;
        const float val = c[mt][nt][r] + bb;
        if (MODE == 1) {
          const int bidx = m >> 12;
          const int s = m & 4095;
          const int hh = n >> 6;
          const int d = n & 63;
          const size_t off =
              ((size_t)(bidx * NHEAD + hh) * SDIM + s) * DHEAD + d;
          short x, y;
          bf16_split(val, x, y);
          oh[off] = x;
          ol[off] = y;
        } else {
          out[(size_t)m * DMODEL + n] = val;
        }
      }
  }
}

// ---------------------------------------------------------------------------
// V transpose: [B,H,S,D] h/l shorts -> [B,H,D,S]. 64x64 tiles via LDS.
// ---------------------------------------------------------------------------
__global__ __launch_bounds__(256) void vtrans_kernel(
    const short* __restrict__ vh, const short* __restrict__ vl,
    short* __restrict__ vth, short* __restrict__ vtl) {
  __shared__ short Th[64 * 72], Tl[64 * 72];
  const int tid = threadIdx.x;
  const int s0 = blockIdx.x * 64;
  const int h = blockIdx.y;
  const int b = blockIdx.z;
  const size_t base = (size_t)(b * NHEAD + h) * SDIM * DHEAD;

  {
    const int s = tid >> 2;
    const int c = tid & 3;
    const short* srcH = vh + base + (size_t)(s0 + s) * DHEAD + c * 16;
    const short* srcL = vl + base + (size_t)(s0 + s) * DHEAD + c * 16;
    *(short8*)&Th[s * 72 + c * 16] = *(const short8*)srcH;
    *(short8*)&Th[s * 72 + c * 16 + 8] = *(const short8*)(srcH + 8);
    *(short8*)&Tl[s * 72 + c * 16] = *(const short8*)srcL;
    *(short8*)&Tl[s * 72 + c * 16 + 8] = *(const short8*)(srcL + 8);
  }
  __syncthreads();
  {
    const int d = tid & 63;
    const int cw = tid >> 6;
    short8 a0, a1, b0, b1;
#pragma unroll
    for (int i = 0; i < 8; i++) {
      a0[i] = Th[(cw * 16 + i) * 72 + d];
      a1[i] = Th[(cw * 16 + 8 + i) * 72 + d];
      b0[i] = Tl[(cw * 16 + i) * 72 + d];
      b1[i] = Tl[(cw * 16 + 8 + i) * 72 + d];
    }
    short* dstH = vth + base + (size_t)d * SDIM + s0 + cw * 16;
    short* dstL = vtl + base + (size_t)d * SDIM + s0 + cw * 16;
    *(short8*)dstH = a0;
    *(short8*)(dstH + 8) = a1;
    *(short8*)dstL = b0;
    *(short8*)(dstL + 8) = b1;
  }
}

// ---------------------------------------------------------------------------
// Flash attention, bf16x3 via 32x32x16 MFMA, fixed-shift softmax.
// Block: 4 waves; wave owns a 32-q band (q-block 128). K-tile = 64 keys.
// A/B layout: [m|n = lane&31][k = 8*(lane>>5)+j].
// C/D layout: col = lane&31, row = (reg&3)+8*(reg>>2)+4*(lane>>5).
// P round-trip: packed int (bf16h<<16 | bf16l), conflict-free addressing.
// LDS: K h/l + V^T h/l [64][72]s + Ps [128][68]i = 70 KB -> 2 blk/CU.
// ---------------------------------------------------------------------------
#define KP 72
#define VP 72
#define PP 68

__global__ __launch_bounds__(256, 2) void flash_attn_kernel(
    const short* __restrict__ qhh, const short* __restrict__ qhl,
    const short* __restrict__ khh, const short* __restrict__ khl,
    const short* __restrict__ vth, const short* __restrict__ vtl,
    const float* __restrict__ mask, float* __restrict__ ctx) {
  __shared__ short Ksh[64 * KP], Ksl[64 * KP];
  __shared__ short Vsh[64 * VP], Vsl[64 * VP];
  __shared__ int Ps[128 * PP];  // packed (h<<16)|l

  const int tid = threadIdx.x;
  const int lane = tid & 63;
  const int w = tid >> 6;
  const int l31 = lane & 31;
  const int half = lane >> 5;  // 0/1
  const int q0 = blockIdx.x * 128;
  const int h = blockIdx.y;
  const int b = blockIdx.z;

  const size_t base = (size_t)(b * NHEAD + h) * SDIM * DHEAD;
  const short* Qh = qhh + base;
  const short* Ql = qhl + base;
  const short* Kh = khh + base;
  const short* Kl = khl + base;
  const short* Vh = vth + base;  // [D][S]
  const short* Vl = vtl + base;
  const float* mb = mask + (size_t)b * SDIM;

  // Q A-frags: qf[c] = Q[q = q0+w*32+l31][d = 16c + 8*half + j]
  short8 qfh[4], qfl[4];
  {
    const size_t row = q0 + w * 32 + l31;
#pragma unroll
    for (int c = 0; c < 4; c++) {
      qfh[c] = *(const short8*)(Qh + row * DHEAD + c * 16 + half * 8);
      qfl[c] = *(const short8*)(Ql + row * DHEAD + c * 16 + half * 8);
    }
  }

  f32x16 o[2], lsum;
#pragma unroll
  for (int i = 0; i < 16; i++) {
    o[0][i] = 0.f;
    o[1][i] = 0.f;
    lsum[i] = 0.f;
  }

  short8 onesb;
#pragma unroll
  for (int j = 0; j < 8; j++) onesb[j] = (short)0x3F80;  // bf16 1.0

  // Staging: 64x64-short planes, 16 shorts (2 b128) per thread per plane.
  const int sr = tid >> 2;
  const int sc = (tid & 3) * 16;

  for (int kt = 0; kt < SDIM / 64; kt++) {
    const int k0 = kt * 64;
    {
      const short8 a0 = *(const short8*)(Kh + (size_t)(k0 + sr) * DHEAD + sc);
      const short8 a1 = *(const short8*)(Kh + (size_t)(k0 + sr) * DHEAD + sc + 8);
      const short8 b0 = *(const short8*)(Kl + (size_t)(k0 + sr) * DHEAD + sc);
      const short8 b1 = *(const short8*)(Kl + (size_t)(k0 + sr) * DHEAD + sc + 8);
      const short8 c0 = *(const short8*)(Vh + (size_t)sr * SDIM + k0 + sc);
      const short8 c1 = *(const short8*)(Vh + (size_t)sr * SDIM + k0 + sc + 8);
      const short8 d0 = *(const short8*)(Vl + (size_t)sr * SDIM + k0 + sc);
      const short8 d1 = *(const short8*)(Vl + (size_t)sr * SDIM + k0 + sc + 8);
      *(short8*)&Ksh[sr * KP + sc] = a0;
      *(short8*)&Ksh[sr * KP + sc + 8] = a1;
      *(short8*)&Ksl[sr * KP + sc] = b0;
      *(short8*)&Ksl[sr * KP + sc + 8] = b1;
      *(short8*)&Vsh[sr * VP + sc] = c0;
      *(short8*)&Vsh[sr * VP + sc + 8] = c1;
      *(short8*)&Vsl[sr * VP + sc] = d0;
      *(short8*)&Vsl[sr * VP + sc + 8] = d1;
    }
    float mv[2];
#pragma unroll
    for (int t = 0; t < 2; t++)
      mv[t] = fmaf(mb[k0 + t * 32 + l31], MASKMUL, -M0C);
    __syncthreads();

    // ---- S = Q K^T (bf16x3): two 32x32 key-tiles ----
#pragma unroll
    for (int t = 0; t < 2; t++) {
      f32x16 acc;
#pragma unroll
      for (int i = 0; i < 16; i++) acc[i] = 0.f;
#pragma unroll
      for (int c = 0; c < 4; c++) {
        const int koff = (t * 32 + l31) * KP + c * 16 + half * 8;
        const short8 kbh = *(const short8*)&Ksh[koff];
        const short8 kbl = *(const short8*)&Ksl[koff];
        acc = MFMA32(qfh[c], kbh, acc);
        acc = MFMA32(qfh[c], kbl, acc);
        acc = MFMA32(qfl[c], kbh, acc);
      }
      // exp2 + pack h/l + store to Ps (conflict-free: key = l31)
#pragma unroll
      for (int reg = 0; reg < 16; reg++) {
        const int row = (reg & 3) + 8 * (reg >> 2) + 4 * half;  // 0..31
        const float p = EXP2F(fmaf(acc[reg], SCALE2, mv[t]));
        short ph, pl;
        bf16_split(p, ph, pl);
        Ps[(w * 32 + row) * PP + t * 32 + l31] =
            (((int)(unsigned short)ph) << 16) | (int)(unsigned short)pl;
      }
    }
    // Same-wave LDS write->read (wave reads only its own 32-row band).

    // ---- P A-frags: unpack packed ints ----
    short8 pah[4], pal[4];
#pragma unroll
    for (int kc = 0; kc < 4; kc++) {
      const int* pr = &Ps[(w * 32 + l31) * PP + kc * 16 + half * 8];
      const i32x4 w0 = *(const i32x4*)pr;
      const i32x4 w1 = *(const i32x4*)(pr + 4);
      short8 ph, pl;
#pragma unroll
      for (int j = 0; j < 4; j++) {
        ph[j] = (short)((unsigned)w0[j] >> 16);
        pl[j] = (short)(w0[j] & 0xffff);
        ph[4 + j] = (short)((unsigned)w1[j] >> 16);
        pl[4 + j] = (short)(w1[j] & 0xffff);
      }
      pah[kc] = ph;
      pal[kc] = pl;
    }

    // ---- l-sum accumulates in a persistent MFMA-ones C-tile ----
#pragma unroll
    for (int kc = 0; kc < 4; kc++) {
      lsum = MFMA32(pah[kc], onesb, lsum);
      lsum = MFMA32(pal[kc], onesb, lsum);
    }

    // ---- O += P V (bf16x3): two 32-d tiles ----
#pragma unroll
    for (int t2 = 0; t2 < 2; t2++)
#pragma unroll
      for (int kc = 0; kc < 4; kc++) {
        const int voff = (t2 * 32 + l31) * VP + kc * 16 + half * 8;
        const short8 vbh = *(const short8*)&Vsh[voff];
        const short8 vbl = *(const short8*)&Vsl[voff];
        o[t2] = MFMA32(pah[kc], vbh, o[t2]);
        o[t2] = MFMA32(pah[kc], vbl, o[t2]);
        o[t2] = MFMA32(pal[kc], vbh, o[t2]);
      }
    __syncthreads();  // all LDS reads done before next staging
  }

  // ---- normalize + write ctx [B, S, H*D] fp32 ----
  float inv[16];
#pragma unroll
  for (int reg = 0; reg < 16; reg++) inv[reg] = 1.f / lsum[reg];
#pragma unroll
  for (int t2 = 0; t2 < 2; t2++)
#pragma unroll
    for (int reg = 0; reg < 16; reg++) {
      const int q = q0 + w * 32 + (reg & 3) + 8 * (reg >> 2) + 4 * half;
      const int d = t2 * 32 + l31;
      ctx[((size_t)b * SDIM + q) * DMODEL + h * DHEAD + d] =
          o[t2][reg] * inv[reg];
    }
}

// ---------------------------------------------------------------------------
extern "C" void kernel_launch(void* const* d_in, const int* in_sizes, int n_in,
                              void* d_out, int out_size, void* d_ws,
                              size_t ws_size, hipStream_t stream) {
  const float* q = (const float*)d_in[0];
  const float* k = (const float*)d_in[1];
  const float* v = (const float*)d_in[2];
  const float* mask = (const float*)d_in[3];
  const float* Wq = (const float*)d_in[4];
  const float* bq = (const float*)d_in[5];
  const float* Wk = (const float*)d_in[6];
  const float* bk = (const float*)d_in[7];
  const float* Wv = (const float*)d_in[8];
  const float* bv = (const float*)d_in[9];
  const float* Wo = (const float*)d_in[10];
  const float* bo = (const float*)d_in[11];
  float* out = (float*)d_out;

  char* W = (char*)d_ws;
  const size_t SZB = (size_t)MROWS * DMODEL * sizeof(short);  // 8 MB
  short* q_h = (short*)(W + 0 * SZB);
  short* q_l = (short*)(W + 1 * SZB);
  short* k_h = (short*)(W + 2 * SZB);
  short* k_l = (short*)(W + 3 * SZB);
  short* v_h = (short*)(W + 4 * SZB);
  short* v_l = (short*)(W + 5 * SZB);
  short* vt_h = (short*)(W + 6 * SZB);
  short* vt_l = (short*)(W + 7 * SZB);
  float* ctx = (float*)(W + 4 * SZB);  // aliases v_h/v_l (dead after vtrans)

  const size_t WSZ = (size_t)DMODEL * DMODEL * sizeof(short);  // 512 KB
  char* WT = W + 8 * SZB;
  short* wtq_h = (short*)(WT + 0 * WSZ);
  short* wtq_l = (short*)(WT + 1 * WSZ);
  short* wtk_h = (short*)(WT + 2 * WSZ);
  short* wtk_l = (short*)(WT + 3 * WSZ);
  short* wtv_h = (short*)(WT + 4 * WSZ);
  short* wtv_l = (short*)(WT + 5 * WSZ);
  short* wto_h = (short*)(WT + 6 * WSZ);
  short* wto_l = (short*)(WT + 7 * WSZ);

  wsplit_kernel<<<dim3(DMODEL / 64, DMODEL / 64, 4), 256, 0, stream>>>(
      Wq, Wk, Wv, Wo, wtq_h, wtq_l, wtk_h, wtk_l, wtv_h, wtv_l, wto_h, wto_l);

  const dim3 gproj(MROWS / 64, DMODEL / 64);  // 128 x 8
  proj_mfma_kernel<1><<<gproj, 256, 0, stream>>>(q, wtq_h, wtq_l, bq, nullptr,
                                                 q_h, q_l);
  proj_mfma_kernel<1><<<gproj, 256, 0, stream>>>(k, wtk_h, wtk_l, bk, nullptr,
                                                 k_h, k_l);
  proj_mfma_kernel<1><<<gproj, 256, 0, stream>>>(v, wtv_h, wtv_l, bv, nullptr,
                                                 v_h, v_l);

  vtrans_kernel<<<dim3(SDIM / 64, NHEAD, BDIM), 256, 0, stream>>>(v_h, v_l,
                                                                  vt_h, vt_l);

  flash_attn_kernel<<<dim3(SDIM / 128, NHEAD, BDIM), 256, 0, stream>>>(
      q_h, q_l, k_h, k_l, vt_h, vt_l, mask, ctx);

  proj_mfma_kernel<0><<<gproj, 256, 0, stream>>>(ctx, wto_h, wto_l, bo, out,
                                                 nullptr, nullptr);
}